// Round 1
// 2401.676 us; speedup vs baseline: 1.3475x; 1.3475x over previous
//
#include <hip/hip_runtime.h>

#define DIMC 1024
#define SEQ  2048
#define NHEAD 16
#define BATCH 8

// ---------------------------------------------------------------- helpers
__device__ __forceinline__ void gll4(const float* g, float* l) {
  __builtin_amdgcn_global_load_lds(
      (const __attribute__((address_space(1))) void*)g,
      (__attribute__((address_space(3))) void*)l, 4, 0, 0);
}
__device__ __forceinline__ void gll16(const unsigned short* g, unsigned short* l) {
  __builtin_amdgcn_global_load_lds(
      (const __attribute__((address_space(1))) void*)g,
      (__attribute__((address_space(3))) void*)l, 16, 0, 0);
}

// waitcnt immediates (gfx9 encoding: vm[3:0]=b3:0, exp=b6:4, lgkm=b11:8, vm[5:4]=b15:14)
#define WAIT_VM21   0x4F75  // vmcnt<=21 (3 vmem ops/iter * (PD-1) iters in flight)
#define WAIT_VM0    0x0F70  // vmcnt<=0

// fp32 <-> bf16 (RNE)
__device__ __forceinline__ unsigned short f2bf(float f) {
  unsigned u = __float_as_uint(f);
  return (unsigned short)((u + 0x7fffu + ((u >> 16) & 1u)) >> 16);
}
__device__ __forceinline__ float bf2f(unsigned short h) {
  return __uint_as_float(((unsigned)h) << 16);
}

typedef __attribute__((ext_vector_type(8))) short  bf16x8;
typedef __attribute__((ext_vector_type(4))) float  floatx4;

// quad (lanes ^1, ^2) sum via DPP quad_perm — stays on VALU, no LDS latency
__device__ __forceinline__ float quad_sum(float x) {
  int y1 = __builtin_amdgcn_update_dpp(0, __float_as_int(x), 0xB1, 0xF, 0xF, true); // perm(1,0,3,2)
  float x1 = x + __int_as_float(y1);
  int y2 = __builtin_amdgcn_update_dpp(0, __float_as_int(x1), 0x4E, 0xF, 0xF, true); // perm(2,3,0,1)
  return x1 + __int_as_float(y2);
}

// ---------------------------------------------------------------- split fp32 -> bf16 hi/lo
__global__ __launch_bounds__(256)
void cvt_split(const float* __restrict__ in, unsigned short* __restrict__ hi,
               unsigned short* __restrict__ lo, int n4)
{
  int i = blockIdx.x * 256 + threadIdx.x;
  if (i >= n4) return;
  float4 f = ((const float4*)in)[i];
  unsigned short h0 = f2bf(f.x), h1 = f2bf(f.y), h2 = f2bf(f.z), h3 = f2bf(f.w);
  unsigned short l0 = f2bf(f.x - bf2f(h0)), l1 = f2bf(f.y - bf2f(h1));
  unsigned short l2 = f2bf(f.z - bf2f(h2)), l3 = f2bf(f.w - bf2f(h3));
  ushort4 H; H.x = h0; H.y = h1; H.z = h2; H.w = h3;
  ushort4 L; L.x = l0; L.y = l1; L.z = l2; L.w = l3;
  ((ushort4*)hi)[i] = H;
  ((ushort4*)lo)[i] = L;
}

// ---------------------------------------------------------------- pack Wa/Wb into padded 128x1024
__global__ void pack_ab_kernel(const float* __restrict__ Wa, const float* __restrict__ ba,
                               const float* __restrict__ Wb, const float* __restrict__ bb,
                               float* __restrict__ Wab, float* __restrict__ bab)
{
  int i = blockIdx.x * 256 + threadIdx.x;
  if (i < 128 * 1024) {
    int row = i >> 10, col = i & 1023;
    float v = 0.0f;
    if (row < 16) v = Wa[(row << 10) + col];
    else if (row < 32) v = Wb[((row - 16) << 10) + col];
    Wab[i] = v;
  } else {
    int j = i - 128 * 1024;
    if (j < 128) {
      float v = 0.0f;
      if (j < 16) v = ba[j];
      else if (j < 32) v = bb[j - 16];
      bab[j] = v;
    }
  }
}

// ---------------------------------------------------------------- split-bf16 MFMA GEMM
// C[M,N] = act(A @ B^T + bias), A: MxK (bf16 hi/lo), B: NxK (bf16 hi/lo), fp32 out.
__global__ __launch_bounds__(256, 2)
void gemm_bf16x3(const unsigned short* __restrict__ Ah, const unsigned short* __restrict__ Al,
                 const unsigned short* __restrict__ Bh, const unsigned short* __restrict__ Bl,
                 const float* __restrict__ bias, float* __restrict__ C,
                 int K, int ldc, int nvalid, int act)
{
  __shared__ unsigned short sAh[4096], sAl[4096], sBh[4096], sBl[4096];
  const int tid  = threadIdx.x;
  const int lane = tid & 63;
  const int w    = tid >> 6;

  const int crow = tid >> 2;
  const int kel  = (tid & 3) << 3;
  const unsigned short* pAh0 = Ah + (size_t)(blockIdx.x * 128 + crow) * K + kel;
  const unsigned short* pAh1 = Ah + (size_t)(blockIdx.x * 128 + 64 + crow) * K + kel;
  const unsigned short* pAl0 = Al + (size_t)(blockIdx.x * 128 + crow) * K + kel;
  const unsigned short* pAl1 = Al + (size_t)(blockIdx.x * 128 + 64 + crow) * K + kel;
  const unsigned short* pBh0 = Bh + (size_t)(blockIdx.y * 128 + crow) * K + kel;
  const unsigned short* pBh1 = Bh + (size_t)(blockIdx.y * 128 + 64 + crow) * K + kel;
  const unsigned short* pBl0 = Bl + (size_t)(blockIdx.y * 128 + crow) * K + kel;
  const unsigned short* pBl1 = Bl + (size_t)(blockIdx.y * 128 + 64 + crow) * K + kel;
  const int wb = (tid & 192) * 8;

  floatx4 acc[16];
  #pragma unroll
  for (int i = 0; i < 16; ++i) acc[i] = (floatx4){0.f, 0.f, 0.f, 0.f};

  const int mq = (w & 1) << 6;
  const int nq = (w >> 1) << 6;
  const int fr = lane & 15;
  const int fk = (lane >> 4) << 3;

  for (int kt = 0; kt < K; kt += 32) {
    __syncthreads();
    gll16(pAh0, sAh + wb); gll16(pAh1, sAh + 2048 + wb);
    gll16(pAl0, sAl + wb); gll16(pAl1, sAl + 2048 + wb);
    gll16(pBh0, sBh + wb); gll16(pBh1, sBh + 2048 + wb);
    gll16(pBl0, sBl + wb); gll16(pBl1, sBl + 2048 + wb);
    pAh0 += 32; pAh1 += 32; pAl0 += 32; pAl1 += 32;
    pBh0 += 32; pBh1 += 32; pBl0 += 32; pBl1 += 32;
    __syncthreads();

    bf16x8 ah[4], al[4], bh[4], bl[4];
    #pragma unroll
    for (int mi = 0; mi < 4; ++mi) {
      int off = (mq + mi * 16 + fr) * 32 + fk;
      ah[mi] = *(const bf16x8*)&sAh[off];
      al[mi] = *(const bf16x8*)&sAl[off];
    }
    #pragma unroll
    for (int ni = 0; ni < 4; ++ni) {
      int off = (nq + ni * 16 + fr) * 32 + fk;
      bh[ni] = *(const bf16x8*)&sBh[off];
      bl[ni] = *(const bf16x8*)&sBl[off];
    }
    #pragma unroll
    for (int mi = 0; mi < 4; ++mi)
      #pragma unroll
      for (int ni = 0; ni < 4; ++ni) {
        floatx4 c = acc[mi * 4 + ni];
        c = __builtin_amdgcn_mfma_f32_16x16x32_bf16(ah[mi], bh[ni], c, 0, 0, 0);
        c = __builtin_amdgcn_mfma_f32_16x16x32_bf16(ah[mi], bl[ni], c, 0, 0, 0);
        c = __builtin_amdgcn_mfma_f32_16x16x32_bf16(al[mi], bh[ni], c, 0, 0, 0);
        acc[mi * 4 + ni] = c;
      }
  }

  const int mbase = blockIdx.x * 128 + mq + ((lane >> 4) << 2);
  const int nbase = blockIdx.y * 128 + nq + (lane & 15);
  #pragma unroll
  for (int ni = 0; ni < 4; ++ni) {
    int n = nbase + ni * 16;
    if (n < nvalid) {
      float bs = bias[n];
      #pragma unroll
      for (int mi = 0; mi < 4; ++mi) {
        #pragma unroll
        for (int r = 0; r < 4; ++r) {
          int m = mbase + mi * 16 + r;
          float val = acc[mi * 4 + ni][r] + bs;
          if (act == 1)      val = val * (1.0f / (1.0f + __expf(-val)));
          else if (act == 2) val = 1.0f / (1.0f + __expf(-val));
          C[(size_t)m * ldc + n] = val;
        }
      }
    }
  }
}

// ---------------------------------------------------------------- depthwise conv(K=4,pad2) + silu + optional l2norm
__global__ __launch_bounds__(256)
void conv_kernel(const float* __restrict__ pre, const float* __restrict__ w,
                 float* __restrict__ out, int do_norm)
{
  __shared__ float red[4];
  const int bt  = blockIdx.x;
  const int t   = bt & (SEQ - 1);
  const int tid = threadIdx.x;
  const int c   = tid << 2;
  const float* rowp = pre + (size_t)bt * DIMC + c;
  const float4 z = make_float4(0.f, 0.f, 0.f, 0.f);
  float4 xm2 = (t >= 2)      ? *(const float4*)(rowp - 2 * DIMC) : z;
  float4 xm1 = (t >= 1)      ? *(const float4*)(rowp - DIMC)     : z;
  float4 x0  =                 *(const float4*)(rowp);
  float4 xp1 = (t + 1 < SEQ) ? *(const float4*)(rowp + DIMC)     : z;
  const float4 w0 = *(const float4*)(w + (size_t)(c + 0) * 4);
  const float4 w1 = *(const float4*)(w + (size_t)(c + 1) * 4);
  const float4 w2 = *(const float4*)(w + (size_t)(c + 2) * 4);
  const float4 w3 = *(const float4*)(w + (size_t)(c + 3) * 4);
  float y0 = xm2.x * w0.x + xm1.x * w0.y + x0.x * w0.z + xp1.x * w0.w;
  float y1 = xm2.y * w1.x + xm1.y * w1.y + x0.y * w1.z + xp1.y * w1.w;
  float y2 = xm2.z * w2.x + xm1.z * w2.y + x0.z * w2.z + xp1.z * w2.w;
  float y3 = xm2.w * w3.x + xm1.w * w3.y + x0.w * w3.z + xp1.w * w3.w;
  y0 = y0 * (1.0f / (1.0f + __expf(-y0)));
  y1 = y1 * (1.0f / (1.0f + __expf(-y1)));
  y2 = y2 * (1.0f / (1.0f + __expf(-y2)));
  y3 = y3 * (1.0f / (1.0f + __expf(-y3)));
  if (do_norm) {
    float ss = y0*y0 + y1*y1 + y2*y2 + y3*y3;
    #pragma unroll
    for (int off = 32; off >= 1; off >>= 1) ss += __shfl_xor(ss, off);
    if ((tid & 63) == 0) red[tid >> 6] = ss;
    __syncthreads();
    float tot = red[0] + red[1] + red[2] + red[3];
    float rn = 1.0f / (sqrtf(tot) + 1e-6f);
    y0 *= rn; y1 *= rn; y2 *= rn; y3 *= rn;
  }
  *(float4*)(out + (size_t)bt * DIMC + c) = make_float4(y0, y1, y2, y3);
}

// ---------------------------------------------------------------- gated delta scan, pass 1 (serial)
// Recurrence only: S(t) = a*S(t-1) + coef_t k_t^T, coef_t = bg*v - a*bg*(S k).
// Emits coef_t (Cf[bh][t][64]) and S checkpoints every 64 steps (SC[bh][c][64][64]).
// One wave per (bh, 16-row group): no barriers, no cross-wave exchange at all.
// The output o is NOT computed here — recomputed in parallel by outp_kernel.
#define PD 8
__global__ __launch_bounds__(64)
void scan2_kernel(const float* __restrict__ k, const float* __restrict__ v,
                  const float* __restrict__ ab, float* __restrict__ Cf,
                  float* __restrict__ SC)
{
  __shared__ float ring[PD][2][64];   // [slot][k|v][64]
  __shared__ float aS[SEQ];
  __shared__ float bSh[SEQ];
  const int blk = blockIdx.x;
  const int bh  = blk >> 2;           // b*16+h
  const int rg  = blk & 3;            // 16-row group
  const int b   = bh >> 4, h = bh & 15;
  const int tid = threadIdx.x;        // 0..63
  const int rr  = tid >> 2;           // 0..15
  const int g   = tid & 3;            // e-quarter
  const int d   = rg * 16 + rr;       // global state row 0..63

  const float* abbase = ab + (size_t)b * SEQ * 32 + h;
  for (int i = tid; i < SEQ; i += 64) {
    aS[i]  = abbase[(size_t)i * 32];
    bSh[i] = abbase[(size_t)i * 32 + 16];
  }
  __syncthreads();

  const size_t base = (size_t)b * SEQ * DIMC + h * 64;
  const float* kp = k + base + tid;
  const float* vp = v + base + tid;

  #pragma unroll
  for (int pt = 0; pt < PD; ++pt) {
    gll4(kp + (size_t)pt * DIMC, &ring[pt][0][0]);
    gll4(vp + (size_t)pt * DIMC, &ring[pt][1][0]);
  }
  __builtin_amdgcn_s_waitcnt(WAIT_VM0);   // drain prologue so early iters are safe
  asm volatile("" ::: "memory");

  float S[16];
  #pragma unroll
  for (int j = 0; j < 16; ++j) S[j] = 0.f;

  float* cfp = Cf + (size_t)bh * SEQ * 64 + d;

  for (int t = 0; t < SEQ; ++t) {
    const int slot = t & (PD - 1);

    if ((t & 63) == 0) {  // checkpoint: state entering chunk c = t>>6
      float4* dst = (float4*)(SC + (((size_t)bh * 32 + (t >> 6)) * 64 + d) * 64 + g * 16);
      dst[0] = make_float4(S[0],  S[1],  S[2],  S[3]);
      dst[1] = make_float4(S[4],  S[5],  S[6],  S[7]);
      dst[2] = make_float4(S[8],  S[9],  S[10], S[11]);
      dst[3] = make_float4(S[12], S[13], S[14], S[15]);
    }

    if (t < SEQ - PD) { __builtin_amdgcn_s_waitcnt(WAIT_VM21); }
    else              { __builtin_amdgcn_s_waitcnt(WAIT_VM0);  }
    asm volatile("" ::: "memory");

    const float a  = aS[t];
    const float bg = bSh[t];
    const float4 k0 = *(const float4*)&ring[slot][0][(g << 4) + 0];
    const float4 k1 = *(const float4*)&ring[slot][0][(g << 4) + 4];
    const float4 k2 = *(const float4*)&ring[slot][0][(g << 4) + 8];
    const float4 k3 = *(const float4*)&ring[slot][0][(g << 4) + 12];
    const float vd = ring[slot][1][d];
    const float kk[16] = {k0.x,k0.y,k0.z,k0.w, k1.x,k1.y,k1.z,k1.w,
                          k2.x,k2.y,k2.z,k2.w, k3.x,k3.y,k3.z,k3.w};

    // sk = S . k over this thread's 16 e-slots, treed (4 accumulators)
    float s0 = fmaf(S[0], kk[0], fmaf(S[4], kk[4], fmaf(S[8],  kk[8],  S[12] * kk[12])));
    float s1 = fmaf(S[1], kk[1], fmaf(S[5], kk[5], fmaf(S[9],  kk[9],  S[13] * kk[13])));
    float s2 = fmaf(S[2], kk[2], fmaf(S[6], kk[6], fmaf(S[10], kk[10], S[14] * kk[14])));
    float s3 = fmaf(S[3], kk[3], fmaf(S[7], kk[7], fmaf(S[11], kk[11], S[15] * kk[15])));
    float sk = quad_sum((s0 + s1) + (s2 + s3));   // DPP quad reduce over the 4 e-quarters

    const float coef = fmaf(-a * bg, sk, bg * vd);
    if (g == 0) cfp[(size_t)t * 64] = coef;

    if (t + PD < SEQ) {
      gll4(kp + (size_t)(t + PD) * DIMC, &ring[slot][0][0]);
      gll4(vp + (size_t)(t + PD) * DIMC, &ring[slot][1][0]);
    }
    asm volatile("" ::: "memory");  // pin stores/loads to their iteration (vmcnt count math)

    #pragma unroll
    for (int j = 0; j < 16; ++j) S[j] = fmaf(a, S[j], coef * kk[j]);
  }
}

// ---------------------------------------------------------------- gated delta scan, pass 2 (parallel)
// Per (bh, chunk of 64): o(t)^T = G_t q_t^T Z + sum_{s<=t} (G_t/G_s)(q_t . coef_s) k_s^T
// with Z the chunk-start checkpoint and G the in-chunk inclusive cumprod of a.
// Three fp32 64x64x64 matmuls per block; all LDS read patterns conflict-free.
__global__ __launch_bounds__(256)
void outp_kernel(const float* __restrict__ q, const float* __restrict__ k,
                 const float* __restrict__ Cf, const float* __restrict__ SC,
                 const float* __restrict__ ab, float* __restrict__ O)
{
  __shared__ float QsT[64 * 64];  // [d][t]
  __shared__ float CP [64 * 64];  // CsT [d][s], then reused as PT [s][t]
  __shared__ float Ks [64 * 64];  // [s][e]
  __shared__ float Zs [64 * 64];  // [d][e]
  __shared__ float av[64], Gv[64], rGv[64];

  const int c   = blockIdx.x;
  const int bh  = blockIdx.y;
  const int b   = bh >> 4, h = bh & 15;
  const int cs  = c << 6;
  const int tid = threadIdx.x;
  const int tl  = tid & 63, th = tid >> 6;

  {
    const float* qr = q  + ((size_t)(b * SEQ + cs + tl)) * DIMC + h * 64 + th * 16;
    const float* cr = Cf + ((size_t)bh * SEQ + cs + tl) * 64 + th * 16;
    #pragma unroll
    for (int u = 0; u < 4; ++u) {
      float4 qv = *(const float4*)(qr + u * 4);
      float4 cv = *(const float4*)(cr + u * 4);
      int dd = th * 16 + u * 4;
      QsT[(dd+0)*64 + tl] = qv.x; QsT[(dd+1)*64 + tl] = qv.y;
      QsT[(dd+2)*64 + tl] = qv.z; QsT[(dd+3)*64 + tl] = qv.w;
      CP [(dd+0)*64 + tl] = cv.x; CP [(dd+1)*64 + tl] = cv.y;
      CP [(dd+2)*64 + tl] = cv.z; CP [(dd+3)*64 + tl] = cv.w;
    }
    const float* kr = k  + ((size_t)(b * SEQ + cs + tl)) * DIMC + h * 64 + th * 16;
    const float* zr = SC + (((size_t)bh * 32 + c) * 64 + tl) * 64 + th * 16;
    #pragma unroll
    for (int u = 0; u < 4; ++u) {
      *(float4*)&Ks[tl * 64 + th * 16 + u * 4] = *(const float4*)(kr + u * 4);
      *(float4*)&Zs[tl * 64 + th * 16 + u * 4] = *(const float4*)(zr + u * 4);
    }
    if (tid < 64) av[tid] = ab[((size_t)(b * SEQ + cs + tid)) * 32 + h];
  }
  __syncthreads();
  if (tid == 0) {
    float g = 1.f;
    for (int t = 0; t < 64; ++t) { g *= av[t]; Gv[t] = fmaxf(g, 1e-37f); }
  }
  __syncthreads();
  if (tid < 64) rGv[tid] = 1.0f / Gv[tid];
  __syncthreads();

  const int t0 = ((tid >> 4) & 3) << 2;   // within-wave t block 0..12; full range via tid>>4
  const int tq = (tid >> 4) << 2;         // 0,4,...,60
  const int s0 = (tid & 15) << 2;
  (void)t0;

  // P[t][s] = q_t . coef_s
  float p[4][4] = {{0.f}};
  #pragma unroll 4
  for (int dd = 0; dd < 64; ++dd) {
    const float4 qv = *(const float4*)&QsT[dd * 64 + tq];
    const float4 cv = *(const float4*)&CP [dd * 64 + s0];
    const float qa[4] = {qv.x, qv.y, qv.z, qv.w};
    const float ca[4] = {cv.x, cv.y, cv.z, cv.w};
    #pragma unroll
    for (int i = 0; i < 4; ++i)
      #pragma unroll
      for (int j = 0; j < 4; ++j)
        p[i][j] = fmaf(qa[i], ca[j], p[i][j]);
  }
  __syncthreads();   // everyone done reading CP as CsT

  // masked decay scale, transpose into CP as PT[s][t]
  #pragma unroll
  for (int i = 0; i < 4; ++i) {
    const float gt = Gv[tq + i];
    #pragma unroll
    for (int j = 0; j < 4; ++j) {
      float vsc = (s0 + j <= tq + i) ? p[i][j] * gt * rGv[s0 + j] : 0.f;
      CP[(s0 + j) * 64 + (tq + i)] = vsc;
    }
  }
  __syncthreads();

  // O[t][e] = sum_s PT[s][t]*K[s][e] + G_t * sum_d Q[t][d]*Z[d][e]
  const int e0 = s0;
  float o[4][4] = {{0.f}};
  #pragma unroll 4
  for (int ss = 0; ss < 64; ++ss) {
    const float4 pv = *(const float4*)&CP[ss * 64 + tq];
    const float4 kv = *(const float4*)&Ks[ss * 64 + e0];
    const float pa[4] = {pv.x, pv.y, pv.z, pv.w};
    const float ka[4] = {kv.x, kv.y, kv.z, kv.w};
    #pragma unroll
    for (int i = 0; i < 4; ++i)
      #pragma unroll
      for (int j = 0; j < 4; ++j)
        o[i][j] = fmaf(pa[i], ka[j], o[i][j]);
  }
  float zt[4][4] = {{0.f}};
  #pragma unroll 4
  for (int dd = 0; dd < 64; ++dd) {
    const float4 qv = *(const float4*)&QsT[dd * 64 + tq];
    const float4 zv = *(const float4*)&Zs[dd * 64 + e0];
    const float qa[4] = {qv.x, qv.y, qv.z, qv.w};
    const float za[4] = {zv.x, zv.y, zv.z, zv.w};
    #pragma unroll
    for (int i = 0; i < 4; ++i)
      #pragma unroll
      for (int j = 0; j < 4; ++j)
        zt[i][j] = fmaf(qa[i], za[j], zt[i][j]);
  }
  #pragma unroll
  for (int i = 0; i < 4; ++i) {
    const float gt = Gv[tq + i];
    float4 res;
    res.x = fmaf(gt, zt[i][0], o[i][0]);
    res.y = fmaf(gt, zt[i][1], o[i][1]);
    res.z = fmaf(gt, zt[i][2], o[i][2]);
    res.w = fmaf(gt, zt[i][3], o[i][3]);
    *(float4*)(O + ((size_t)(b * SEQ + cs + tq + i)) * DIMC + h * 64 + e0) = res;
  }
}

// ---------------------------------------------------------------- host
extern "C" void kernel_launch(void* const* d_in, const int* in_sizes, int n_in,
                              void* d_out, int out_size, void* d_ws, size_t ws_size,
                              hipStream_t stream)
{
  const float* x  = (const float*)d_in[0];
  const float* Wq = (const float*)d_in[1];
  const float* bq = (const float*)d_in[2];
  const float* Wk = (const float*)d_in[3];
  const float* bk = (const float*)d_in[4];
  const float* Wv = (const float*)d_in[5];
  const float* bv = (const float*)d_in[6];
  const float* Wa = (const float*)d_in[7];
  const float* ba = (const float*)d_in[8];
  const float* Wb = (const float*)d_in[9];
  const float* bb = (const float*)d_in[10];
  const float* cq = (const float*)d_in[11];
  const float* ck = (const float*)d_in[12];
  const float* cv = (const float*)d_in[13];
  const float* Wo = (const float*)d_in[14];
  const float* bo = (const float*)d_in[15];
  float* out = (float*)d_out;
  float* ws  = (float*)d_ws;

  const size_t per_b = (size_t)SEQ * DIMC;     // 2,097,152
  const size_t wsz   = (size_t)DIMC * DIMC;    // 1,048,576

  int bc = BATCH;
  while (bc > 1) {
    size_t fl = 4 * (size_t)bc * per_b + (size_t)bc * SEQ * 32 + 128 * 1024 + 128;
    size_t us = 2 * (size_t)bc * per_b + 8 * wsz + 2 * 128 * 1024;
    if (fl * 4 + us * 2 <= ws_size) break;
    bc >>= 1;
  }

  float* P   = ws;
  float* qb  = P  + (size_t)bc * per_b;
  float* kb  = qb + (size_t)bc * per_b;
  float* vb  = kb + (size_t)bc * per_b;
  float* abb = vb + (size_t)bc * per_b;
  float* Wab = abb + (size_t)bc * SEQ * 32;
  float* bab = Wab + 128 * 1024;
  unsigned short* xh   = (unsigned short*)(bab + 128);
  unsigned short* xl   = xh  + (size_t)bc * per_b;
  unsigned short* wqh  = xl  + (size_t)bc * per_b;
  unsigned short* wql  = wqh + wsz;
  unsigned short* wkh  = wql + wsz;
  unsigned short* wkl  = wkh + wsz;
  unsigned short* wvh  = wkl + wsz;
  unsigned short* wvl  = wvh + wsz;
  unsigned short* woh  = wvl + wsz;
  unsigned short* wol  = woh + wsz;
  unsigned short* wabh = wol + wsz;
  unsigned short* wabl = wabh + 128 * 1024;

  // scan-phase aliases (dead regions reused; zero extra workspace):
  //  coef  (bc*per_b floats)  -> xh/xl region (x splits dead after gate GEMM)
  //  checkpoints (bc*per_b)   -> P (dead between v-conv and output recompute)
  //  O output                 -> vb (v dead after scan pass 1)
  float* Cf  = (float*)xh;
  float* SCp = P;

  pack_ab_kernel<<<513, 256, 0, stream>>>(Wa, ba, Wb, bb, Wab, bab);
  cvt_split<<<(int)(wsz / 4 + 255) / 256, 256, 0, stream>>>(Wq, wqh, wql, (int)(wsz / 4));
  cvt_split<<<(int)(wsz / 4 + 255) / 256, 256, 0, stream>>>(Wk, wkh, wkl, (int)(wsz / 4));
  cvt_split<<<(int)(wsz / 4 + 255) / 256, 256, 0, stream>>>(Wv, wvh, wvl, (int)(wsz / 4));
  cvt_split<<<(int)(wsz / 4 + 255) / 256, 256, 0, stream>>>(Wo, woh, wol, (int)(wsz / 4));
  cvt_split<<<(128 * 1024 / 4 + 255) / 256, 256, 0, stream>>>(Wab, wabh, wabl, 128 * 1024 / 4);

  for (int b0 = 0; b0 < BATCH; b0 += bc) {
    const float* xb = x + (size_t)b0 * per_b;
    const int M = bc * SEQ;
    const int n4 = (int)((size_t)bc * per_b / 4);
    dim3 gg(M / 128, DIMC / 128);
    dim3 gab(M / 128, 1);

    cvt_split<<<(n4 + 255) / 256, 256, 0, stream>>>(xb, xh, xl, n4);

    // q path
    gemm_bf16x3<<<gg, 256, 0, stream>>>(xh, xl, wqh, wql, bq, P, DIMC, DIMC, DIMC, 1);
    conv_kernel<<<dim3(M), 256, 0, stream>>>(P, cq, qb, 1);
    // k path
    gemm_bf16x3<<<gg, 256, 0, stream>>>(xh, xl, wkh, wkl, bk, P, DIMC, DIMC, DIMC, 1);
    conv_kernel<<<dim3(M), 256, 0, stream>>>(P, ck, kb, 1);
    // v path
    gemm_bf16x3<<<gg, 256, 0, stream>>>(xh, xl, wvh, wvl, bv, P, DIMC, DIMC, DIMC, 1);
    conv_kernel<<<dim3(M), 256, 0, stream>>>(P, cv, vb, 0);
    // gates
    gemm_bf16x3<<<gab, 256, 0, stream>>>(xh, xl, wabh, wabl, bab, abb, DIMC, 32, 32, 2);
    // recurrence pass 1: coef + checkpoints (serial, barrier-free)
    scan2_kernel<<<dim3(bc * NHEAD * 4), 64, 0, stream>>>(kb, vb, abb, Cf, SCp);
    // recurrence pass 2: recompute outputs in parallel -> vb
    outp_kernel<<<dim3(SEQ / 64, bc * NHEAD), 256, 0, stream>>>(qb, kb, Cf, SCp, abb, vb);
    // output projection
    cvt_split<<<(n4 + 255) / 256, 256, 0, stream>>>(vb, xh, xl, n4);
    gemm_bf16x3<<<gg, 256, 0, stream>>>(xh, xl, woh, wol, bo, out + (size_t)b0 * per_b, DIMC, DIMC, DIMC, 0);
  }
}

// Round 2
// 1808.462 us; speedup vs baseline: 1.7895x; 1.3280x over previous
//
#include <hip/hip_runtime.h>

#define DIMC 1024
#define SEQ  2048
#define NHEAD 16
#define BATCH 8

// ---------------------------------------------------------------- helpers
__device__ __forceinline__ void gll4(const float* g, float* l) {
  __builtin_amdgcn_global_load_lds(
      (const __attribute__((address_space(1))) void*)g,
      (__attribute__((address_space(3))) void*)l, 4, 0, 0);
}
__device__ __forceinline__ void gll16(const unsigned short* g, unsigned short* l) {
  __builtin_amdgcn_global_load_lds(
      (const __attribute__((address_space(1))) void*)g,
      (__attribute__((address_space(3))) void*)l, 16, 0, 0);
}

// waitcnt immediates (gfx9 encoding: vm[3:0]=b3:0, exp=b6:4, lgkm=b11:8, vm[5:4]=b15:14)
// ring FIFO per step = {coef store, k load, v load} -> entries younger than the
// (t+1) load pair = 3*(PD-1) = 45 for PD=16.
#define WAIT_VM45   0x8F7D  // vmcnt<=45
#define WAIT_VM0    0x0F70  // vmcnt<=0

// fp32 <-> bf16 (RNE)
__device__ __forceinline__ unsigned short f2bf(float f) {
  unsigned u = __float_as_uint(f);
  return (unsigned short)((u + 0x7fffu + ((u >> 16) & 1u)) >> 16);
}
__device__ __forceinline__ float bf2f(unsigned short h) {
  return __uint_as_float(((unsigned)h) << 16);
}

typedef __attribute__((ext_vector_type(8))) short  bf16x8;
typedef __attribute__((ext_vector_type(4))) float  floatx4;

// sum over 8 contiguous (8-aligned) lanes, pure DPP: ^1, ^2, then half-row mirror
__device__ __forceinline__ float oct_sum(float x) {
  int t1 = __builtin_amdgcn_update_dpp(0, __float_as_int(x), 0xB1, 0xF, 0xF, true);   // quad_perm(1,0,3,2)
  float x1 = x + __int_as_float(t1);
  int t2 = __builtin_amdgcn_update_dpp(0, __float_as_int(x1), 0x4E, 0xF, 0xF, true);  // quad_perm(2,3,0,1)
  float x2 = x1 + __int_as_float(t2);
  int t3 = __builtin_amdgcn_update_dpp(0, __float_as_int(x2), 0x141, 0xF, 0xF, true); // row_half_mirror
  return x2 + __int_as_float(t3);
}

// ---------------------------------------------------------------- split fp32 -> bf16 hi/lo
__global__ __launch_bounds__(256)
void cvt_split(const float* __restrict__ in, unsigned short* __restrict__ hi,
               unsigned short* __restrict__ lo, int n4)
{
  int i = blockIdx.x * 256 + threadIdx.x;
  if (i >= n4) return;
  float4 f = ((const float4*)in)[i];
  unsigned short h0 = f2bf(f.x), h1 = f2bf(f.y), h2 = f2bf(f.z), h3 = f2bf(f.w);
  unsigned short l0 = f2bf(f.x - bf2f(h0)), l1 = f2bf(f.y - bf2f(h1));
  unsigned short l2 = f2bf(f.z - bf2f(h2)), l3 = f2bf(f.w - bf2f(h3));
  ushort4 H; H.x = h0; H.y = h1; H.z = h2; H.w = h3;
  ushort4 L; L.x = l0; L.y = l1; L.z = l2; L.w = l3;
  ((ushort4*)hi)[i] = H;
  ((ushort4*)lo)[i] = L;
}

// ---------------------------------------------------------------- pack Wa/Wb into padded 128x1024
__global__ void pack_ab_kernel(const float* __restrict__ Wa, const float* __restrict__ ba,
                               const float* __restrict__ Wb, const float* __restrict__ bb,
                               float* __restrict__ Wab, float* __restrict__ bab)
{
  int i = blockIdx.x * 256 + threadIdx.x;
  if (i < 128 * 1024) {
    int row = i >> 10, col = i & 1023;
    float v = 0.0f;
    if (row < 16) v = Wa[(row << 10) + col];
    else if (row < 32) v = Wb[((row - 16) << 10) + col];
    Wab[i] = v;
  } else {
    int j = i - 128 * 1024;
    if (j < 128) {
      float v = 0.0f;
      if (j < 16) v = ba[j];
      else if (j < 32) v = bb[j - 16];
      bab[j] = v;
    }
  }
}

// ---------------------------------------------------------------- split-bf16 MFMA GEMM
// C[M,N] = act(A @ B^T + bias), A: MxK (bf16 hi/lo), B: NxK (bf16 hi/lo), fp32 out.
__global__ __launch_bounds__(256, 2)
void gemm_bf16x3(const unsigned short* __restrict__ Ah, const unsigned short* __restrict__ Al,
                 const unsigned short* __restrict__ Bh, const unsigned short* __restrict__ Bl,
                 const float* __restrict__ bias, float* __restrict__ C,
                 int K, int ldc, int nvalid, int act)
{
  __shared__ unsigned short sAh[4096], sAl[4096], sBh[4096], sBl[4096];
  const int tid  = threadIdx.x;
  const int lane = tid & 63;
  const int w    = tid >> 6;

  const int crow = tid >> 2;
  const int kel  = (tid & 3) << 3;
  const unsigned short* pAh0 = Ah + (size_t)(blockIdx.x * 128 + crow) * K + kel;
  const unsigned short* pAh1 = Ah + (size_t)(blockIdx.x * 128 + 64 + crow) * K + kel;
  const unsigned short* pAl0 = Al + (size_t)(blockIdx.x * 128 + crow) * K + kel;
  const unsigned short* pAl1 = Al + (size_t)(blockIdx.x * 128 + 64 + crow) * K + kel;
  const unsigned short* pBh0 = Bh + (size_t)(blockIdx.y * 128 + crow) * K + kel;
  const unsigned short* pBh1 = Bh + (size_t)(blockIdx.y * 128 + 64 + crow) * K + kel;
  const unsigned short* pBl0 = Bl + (size_t)(blockIdx.y * 128 + crow) * K + kel;
  const unsigned short* pBl1 = Bl + (size_t)(blockIdx.y * 128 + 64 + crow) * K + kel;
  const int wb = (tid & 192) * 8;

  floatx4 acc[16];
  #pragma unroll
  for (int i = 0; i < 16; ++i) acc[i] = (floatx4){0.f, 0.f, 0.f, 0.f};

  const int mq = (w & 1) << 6;
  const int nq = (w >> 1) << 6;
  const int fr = lane & 15;
  const int fk = (lane >> 4) << 3;

  for (int kt = 0; kt < K; kt += 32) {
    __syncthreads();
    gll16(pAh0, sAh + wb); gll16(pAh1, sAh + 2048 + wb);
    gll16(pAl0, sAl + wb); gll16(pAl1, sAl + 2048 + wb);
    gll16(pBh0, sBh + wb); gll16(pBh1, sBh + 2048 + wb);
    gll16(pBl0, sBl + wb); gll16(pBl1, sBl + 2048 + wb);
    pAh0 += 32; pAh1 += 32; pAl0 += 32; pAl1 += 32;
    pBh0 += 32; pBh1 += 32; pBl0 += 32; pBl1 += 32;
    __syncthreads();

    bf16x8 ah[4], al[4], bh[4], bl[4];
    #pragma unroll
    for (int mi = 0; mi < 4; ++mi) {
      int off = (mq + mi * 16 + fr) * 32 + fk;
      ah[mi] = *(const bf16x8*)&sAh[off];
      al[mi] = *(const bf16x8*)&sAl[off];
    }
    #pragma unroll
    for (int ni = 0; ni < 4; ++ni) {
      int off = (nq + ni * 16 + fr) * 32 + fk;
      bh[ni] = *(const bf16x8*)&sBh[off];
      bl[ni] = *(const bf16x8*)&sBl[off];
    }
    #pragma unroll
    for (int mi = 0; mi < 4; ++mi)
      #pragma unroll
      for (int ni = 0; ni < 4; ++ni) {
        floatx4 c = acc[mi * 4 + ni];
        c = __builtin_amdgcn_mfma_f32_16x16x32_bf16(ah[mi], bh[ni], c, 0, 0, 0);
        c = __builtin_amdgcn_mfma_f32_16x16x32_bf16(ah[mi], bl[ni], c, 0, 0, 0);
        c = __builtin_amdgcn_mfma_f32_16x16x32_bf16(al[mi], bh[ni], c, 0, 0, 0);
        acc[mi * 4 + ni] = c;
      }
  }

  const int mbase = blockIdx.x * 128 + mq + ((lane >> 4) << 2);
  const int nbase = blockIdx.y * 128 + nq + (lane & 15);
  #pragma unroll
  for (int ni = 0; ni < 4; ++ni) {
    int n = nbase + ni * 16;
    if (n < nvalid) {
      float bs = bias[n];
      #pragma unroll
      for (int mi = 0; mi < 4; ++mi) {
        #pragma unroll
        for (int r = 0; r < 4; ++r) {
          int m = mbase + mi * 16 + r;
          float val = acc[mi * 4 + ni][r] + bs;
          if (act == 1)      val = val * (1.0f / (1.0f + __expf(-val)));
          else if (act == 2) val = 1.0f / (1.0f + __expf(-val));
          C[(size_t)m * ldc + n] = val;
        }
      }
    }
  }
}

// ---------------------------------------------------------------- depthwise conv(K=4,pad2) + silu + optional l2norm
__global__ __launch_bounds__(256)
void conv_kernel(const float* __restrict__ pre, const float* __restrict__ w,
                 float* __restrict__ out, int do_norm)
{
  __shared__ float red[4];
  const int bt  = blockIdx.x;
  const int t   = bt & (SEQ - 1);
  const int tid = threadIdx.x;
  const int c   = tid << 2;
  const float* rowp = pre + (size_t)bt * DIMC + c;
  const float4 z = make_float4(0.f, 0.f, 0.f, 0.f);
  float4 xm2 = (t >= 2)      ? *(const float4*)(rowp - 2 * DIMC) : z;
  float4 xm1 = (t >= 1)      ? *(const float4*)(rowp - DIMC)     : z;
  float4 x0  =                 *(const float4*)(rowp);
  float4 xp1 = (t + 1 < SEQ) ? *(const float4*)(rowp + DIMC)     : z;
  const float4 w0 = *(const float4*)(w + (size_t)(c + 0) * 4);
  const float4 w1 = *(const float4*)(w + (size_t)(c + 1) * 4);
  const float4 w2 = *(const float4*)(w + (size_t)(c + 2) * 4);
  const float4 w3 = *(const float4*)(w + (size_t)(c + 3) * 4);
  float y0 = xm2.x * w0.x + xm1.x * w0.y + x0.x * w0.z + xp1.x * w0.w;
  float y1 = xm2.y * w1.x + xm1.y * w1.y + x0.y * w1.z + xp1.y * w1.w;
  float y2 = xm2.z * w2.x + xm1.z * w2.y + x0.z * w2.z + xp1.z * w2.w;
  float y3 = xm2.w * w3.x + xm1.w * w3.y + x0.w * w3.z + xp1.w * w3.w;
  y0 = y0 * (1.0f / (1.0f + __expf(-y0)));
  y1 = y1 * (1.0f / (1.0f + __expf(-y1)));
  y2 = y2 * (1.0f / (1.0f + __expf(-y2)));
  y3 = y3 * (1.0f / (1.0f + __expf(-y3)));
  if (do_norm) {
    float ss = y0*y0 + y1*y1 + y2*y2 + y3*y3;
    #pragma unroll
    for (int off = 32; off >= 1; off >>= 1) ss += __shfl_xor(ss, off);
    if ((tid & 63) == 0) red[tid >> 6] = ss;
    __syncthreads();
    float tot = red[0] + red[1] + red[2] + red[3];
    float rn = 1.0f / (sqrtf(tot) + 1e-6f);
    y0 *= rn; y1 *= rn; y2 *= rn; y3 *= rn;
  }
  *(float4*)(out + (size_t)bt * DIMC + c) = make_float4(y0, y1, y2, y3);
}

// ---------------------------------------------------------------- gated delta scan, pass 1 (serial)
// S(t) = a*S(t-1) + coef_t k_t^T, coef_t = bg*v - a*bg*(S k).
// Emits coef_t (Cf[bh][t][64]) and S checkpoints every 64 steps (SC[bh][c][64][64]).
// Grid: (bh * 8) single-wave blocks; wave = 8 d-rows x 8 e-octants, 8 S/thread.
// LDS->reg reads are pipelined one step ahead; e-reduce is 3 DPP rounds.
#define PD 16
__global__ __launch_bounds__(64)
void scan2_kernel(const float* __restrict__ k, const float* __restrict__ v,
                  const float* __restrict__ ab, float* __restrict__ Cf,
                  float* __restrict__ SC)
{
  __shared__ float ring[PD][2][64];   // [slot][k|v][64]
  __shared__ float aS[SEQ];
  __shared__ float bSh[SEQ];
  const int blk = blockIdx.x;
  const int bh  = blk >> 3;           // b*16+h
  const int dg  = blk & 7;            // 8-row group
  const int b   = bh >> 4, h = bh & 15;
  const int tid = threadIdx.x;        // 0..63, one wave
  const int dl  = tid >> 3;           // 0..7
  const int eh  = tid & 7;            // e-octant
  const int d   = dg * 8 + dl;        // global state row 0..63
  const int e0  = eh * 8;

  const float* abbase = ab + (size_t)b * SEQ * 32 + h;
  for (int i = tid; i < SEQ; i += 64) {
    aS[i]  = abbase[(size_t)i * 32];
    bSh[i] = abbase[(size_t)i * 32 + 16];
  }
  // single wave: compiler inserts lgkmcnt drain before first LDS read

  const size_t base = (size_t)b * SEQ * DIMC + h * 64;
  const float* kp = k + base + tid;
  const float* vp = v + base + tid;

  // zero checkpoint for chunk 0 (state entering t=0)
  {
    float4 z4 = make_float4(0.f, 0.f, 0.f, 0.f);
    float4* dst0 = (float4*)&SC[(((size_t)bh * 32) * 64 + d) * 64 + e0];
    dst0[0] = z4; dst0[1] = z4;
  }

  #pragma unroll
  for (int pt = 0; pt < PD; ++pt) {
    gll4(kp + (size_t)pt * DIMC, &ring[pt][0][0]);
    gll4(vp + (size_t)pt * DIMC, &ring[pt][1][0]);
  }
  __builtin_amdgcn_s_waitcnt(WAIT_VM0);   // drain prologue
  asm volatile("" ::: "memory");

  float S[8];
  #pragma unroll
  for (int j = 0; j < 8; ++j) S[j] = 0.f;

  float* cfp = Cf + (size_t)bh * SEQ * 64 + d;

  // preload regs for t=0
  float4 ka  = *(const float4*)&ring[0][0][e0];
  float4 kb8 = *(const float4*)&ring[0][0][e0 + 4];
  float  vd  = ring[0][1][d];
  float  a   = aS[0];
  float  bg  = bSh[0];

  for (int t = 0; t < SEQ; ++t) {
    // ---- compute with current regs (all in VGPRs already)
    float p0 = fmaf(S[0], ka.x, S[4] * kb8.x);
    float p1 = fmaf(S[1], ka.y, S[5] * kb8.y);
    float p2 = fmaf(S[2], ka.z, S[6] * kb8.z);
    float p3 = fmaf(S[3], ka.w, S[7] * kb8.w);
    float sk = oct_sum((p0 + p1) + (p2 + p3));
    const float coef = fmaf(-a * bg, sk, bg * vd);
    if (eh == 0) cfp[(size_t)t * 64] = coef;
    asm volatile("" ::: "memory");          // keep store before prefetch (FIFO count)

    if (t < SEQ - PD) {
      const int slot = t & (PD - 1);        // = (t+PD) & (PD-1)
      gll4(kp + (size_t)(t + PD) * DIMC, &ring[slot][0][0]);
      gll4(vp + (size_t)(t + PD) * DIMC, &ring[slot][1][0]);
      asm volatile("" ::: "memory");
      __builtin_amdgcn_s_waitcnt(WAIT_VM45);  // guarantees slot (t+1) resident
    } else {
      asm volatile("" ::: "memory");
      __builtin_amdgcn_s_waitcnt(WAIT_VM0);
    }
    asm volatile("" ::: "memory");          // fence: ds_reads below stay below waitcnt

    // ---- pipelined reads for t+1 (latency overlaps S-update + next issue)
    const int sl1 = (t + 1) & (PD - 1);
    const int tn  = (t + 1) & (SEQ - 1);
    const float4 ka_n  = *(const float4*)&ring[sl1][0][e0];
    const float4 kb_n  = *(const float4*)&ring[sl1][0][e0 + 4];
    const float  vd_n  = ring[sl1][1][d];
    const float  a_n   = aS[tn];
    const float  b_n   = bSh[tn];

    // ---- state update (register-only; scheduler overlaps with reads above)
    S[0] = fmaf(a, S[0], coef * ka.x);
    S[1] = fmaf(a, S[1], coef * ka.y);
    S[2] = fmaf(a, S[2], coef * ka.z);
    S[3] = fmaf(a, S[3], coef * ka.w);
    S[4] = fmaf(a, S[4], coef * kb8.x);
    S[5] = fmaf(a, S[5], coef * kb8.y);
    S[6] = fmaf(a, S[6], coef * kb8.z);
    S[7] = fmaf(a, S[7], coef * kb8.w);

    if (((t + 1) & 63) == 0 && (t + 1) < SEQ) {  // checkpoint entering chunk (t+1)>>6
      float4* dst = (float4*)&SC[(((size_t)bh * 32 + ((t + 1) >> 6)) * 64 + d) * 64 + e0];
      dst[0] = make_float4(S[0], S[1], S[2], S[3]);
      dst[1] = make_float4(S[4], S[5], S[6], S[7]);
    }

    ka = ka_n; kb8 = kb_n; vd = vd_n; a = a_n; bg = b_n;
  }
}

// ---------------------------------------------------------------- gated delta scan, pass 2 (parallel)
// Per (bh, chunk of 64): o(t)^T = G_t q_t^T Z + sum_{s<=t} (G_t/G_s)(q_t . coef_s) k_s^T
__global__ __launch_bounds__(256)
void outp_kernel(const float* __restrict__ q, const float* __restrict__ k,
                 const float* __restrict__ Cf, const float* __restrict__ SC,
                 const float* __restrict__ ab, float* __restrict__ O)
{
  __shared__ float QsT[64 * 64];  // [d][t]
  __shared__ float CP [64 * 64];  // CsT [d][s], then reused as PT [s][t]
  __shared__ float Ks [64 * 64];  // [s][e]
  __shared__ float Zs [64 * 64];  // [d][e]
  __shared__ float av[64], Gv[64], rGv[64];

  const int c   = blockIdx.x;
  const int bh  = blockIdx.y;
  const int b   = bh >> 4, h = bh & 15;
  const int cs  = c << 6;
  const int tid = threadIdx.x;
  const int tl  = tid & 63, th = tid >> 6;

  {
    const float* qr = q  + ((size_t)(b * SEQ + cs + tl)) * DIMC + h * 64 + th * 16;
    const float* cr = Cf + ((size_t)bh * SEQ + cs + tl) * 64 + th * 16;
    #pragma unroll
    for (int u = 0; u < 4; ++u) {
      float4 qv = *(const float4*)(qr + u * 4);
      float4 cv = *(const float4*)(cr + u * 4);
      int dd = th * 16 + u * 4;
      QsT[(dd+0)*64 + tl] = qv.x; QsT[(dd+1)*64 + tl] = qv.y;
      QsT[(dd+2)*64 + tl] = qv.z; QsT[(dd+3)*64 + tl] = qv.w;
      CP [(dd+0)*64 + tl] = cv.x; CP [(dd+1)*64 + tl] = cv.y;
      CP [(dd+2)*64 + tl] = cv.z; CP [(dd+3)*64 + tl] = cv.w;
    }
    const float* kr = k  + ((size_t)(b * SEQ + cs + tl)) * DIMC + h * 64 + th * 16;
    const float* zr = SC + (((size_t)bh * 32 + c) * 64 + tl) * 64 + th * 16;
    #pragma unroll
    for (int u = 0; u < 4; ++u) {
      *(float4*)&Ks[tl * 64 + th * 16 + u * 4] = *(const float4*)(kr + u * 4);
      *(float4*)&Zs[tl * 64 + th * 16 + u * 4] = *(const float4*)(zr + u * 4);
    }
    if (tid < 64) av[tid] = ab[((size_t)(b * SEQ + cs + tid)) * 32 + h];
  }
  __syncthreads();
  if (tid == 0) {
    float g = 1.f;
    for (int t = 0; t < 64; ++t) { g *= av[t]; Gv[t] = fmaxf(g, 1e-37f); }
  }
  __syncthreads();
  if (tid < 64) rGv[tid] = 1.0f / Gv[tid];
  __syncthreads();

  const int tq = (tid >> 4) << 2;         // 0,4,...,60
  const int s0 = (tid & 15) << 2;

  // P[t][s] = q_t . coef_s
  float p[4][4] = {{0.f}};
  #pragma unroll 4
  for (int dd = 0; dd < 64; ++dd) {
    const float4 qv = *(const float4*)&QsT[dd * 64 + tq];
    const float4 cv = *(const float4*)&CP [dd * 64 + s0];
    const float qa[4] = {qv.x, qv.y, qv.z, qv.w};
    const float ca[4] = {cv.x, cv.y, cv.z, cv.w};
    #pragma unroll
    for (int i = 0; i < 4; ++i)
      #pragma unroll
      for (int j = 0; j < 4; ++j)
        p[i][j] = fmaf(qa[i], ca[j], p[i][j]);
  }
  __syncthreads();

  #pragma unroll
  for (int i = 0; i < 4; ++i) {
    const float gt = Gv[tq + i];
    #pragma unroll
    for (int j = 0; j < 4; ++j) {
      float vsc = (s0 + j <= tq + i) ? p[i][j] * gt * rGv[s0 + j] : 0.f;
      CP[(s0 + j) * 64 + (tq + i)] = vsc;
    }
  }
  __syncthreads();

  const int e0 = s0;
  float o[4][4] = {{0.f}};
  #pragma unroll 4
  for (int ss = 0; ss < 64; ++ss) {
    const float4 pv = *(const float4*)&CP[ss * 64 + tq];
    const float4 kv = *(const float4*)&Ks[ss * 64 + e0];
    const float pa[4] = {pv.x, pv.y, pv.z, pv.w};
    const float ka[4] = {kv.x, kv.y, kv.z, kv.w};
    #pragma unroll
    for (int i = 0; i < 4; ++i)
      #pragma unroll
      for (int j = 0; j < 4; ++j)
        o[i][j] = fmaf(pa[i], ka[j], o[i][j]);
  }
  float zt[4][4] = {{0.f}};
  #pragma unroll 4
  for (int dd = 0; dd < 64; ++dd) {
    const float4 qv = *(const float4*)&QsT[dd * 64 + tq];
    const float4 zv = *(const float4*)&Zs[dd * 64 + e0];
    const float qa[4] = {qv.x, qv.y, qv.z, qv.w};
    const float za[4] = {zv.x, zv.y, zv.z, zv.w};
    #pragma unroll
    for (int i = 0; i < 4; ++i)
      #pragma unroll
      for (int j = 0; j < 4; ++j)
        zt[i][j] = fmaf(qa[i], za[j], zt[i][j]);
  }
  #pragma unroll
  for (int i = 0; i < 4; ++i) {
    const float gt = Gv[tq + i];
    float4 res;
    res.x = fmaf(gt, zt[i][0], o[i][0]);
    res.y = fmaf(gt, zt[i][1], o[i][1]);
    res.z = fmaf(gt, zt[i][2], o[i][2]);
    res.w = fmaf(gt, zt[i][3], o[i][3]);
    *(float4*)(O + ((size_t)(b * SEQ + cs + tq + i)) * DIMC + h * 64 + e0) = res;
  }
}

// ---------------------------------------------------------------- host
extern "C" void kernel_launch(void* const* d_in, const int* in_sizes, int n_in,
                              void* d_out, int out_size, void* d_ws, size_t ws_size,
                              hipStream_t stream)
{
  const float* x  = (const float*)d_in[0];
  const float* Wq = (const float*)d_in[1];
  const float* bq = (const float*)d_in[2];
  const float* Wk = (const float*)d_in[3];
  const float* bk = (const float*)d_in[4];
  const float* Wv = (const float*)d_in[5];
  const float* bv = (const float*)d_in[6];
  const float* Wa = (const float*)d_in[7];
  const float* ba = (const float*)d_in[8];
  const float* Wb = (const float*)d_in[9];
  const float* bb = (const float*)d_in[10];
  const float* cq = (const float*)d_in[11];
  const float* ck = (const float*)d_in[12];
  const float* cv = (const float*)d_in[13];
  const float* Wo = (const float*)d_in[14];
  const float* bo = (const float*)d_in[15];
  float* out = (float*)d_out;
  float* ws  = (float*)d_ws;

  const size_t per_b = (size_t)SEQ * DIMC;     // 2,097,152
  const size_t wsz   = (size_t)DIMC * DIMC;    // 1,048,576

  int bc = BATCH;
  while (bc > 1) {
    size_t fl = 4 * (size_t)bc * per_b + (size_t)bc * SEQ * 32 + 128 * 1024 + 128;
    size_t us = 2 * (size_t)bc * per_b + 8 * wsz + 2 * 128 * 1024;
    if (fl * 4 + us * 2 <= ws_size) break;
    bc >>= 1;
  }

  float* P   = ws;
  float* qb  = P  + (size_t)bc * per_b;
  float* kb  = qb + (size_t)bc * per_b;
  float* vb  = kb + (size_t)bc * per_b;
  float* abb = vb + (size_t)bc * per_b;
  float* Wab = abb + (size_t)bc * SEQ * 32;
  float* bab = Wab + 128 * 1024;
  unsigned short* xh   = (unsigned short*)(bab + 128);
  unsigned short* xl   = xh  + (size_t)bc * per_b;
  unsigned short* wqh  = xl  + (size_t)bc * per_b;
  unsigned short* wql  = wqh + wsz;
  unsigned short* wkh  = wql + wsz;
  unsigned short* wkl  = wkh + wsz;
  unsigned short* wvh  = wkl + wsz;
  unsigned short* wvl  = wvh + wsz;
  unsigned short* woh  = wvl + wsz;
  unsigned short* wol  = woh + wsz;
  unsigned short* wabh = wol + wsz;
  unsigned short* wabl = wabh + 128 * 1024;

  // scan-phase aliases (dead regions reused):
  //  coef  (bc*per_b floats)  -> xh/xl region
  //  checkpoints (bc*per_b)   -> P
  //  O output                 -> vb
  float* Cf  = (float*)xh;
  float* SCp = P;

  pack_ab_kernel<<<513, 256, 0, stream>>>(Wa, ba, Wb, bb, Wab, bab);
  cvt_split<<<(int)(wsz / 4 + 255) / 256, 256, 0, stream>>>(Wq, wqh, wql, (int)(wsz / 4));
  cvt_split<<<(int)(wsz / 4 + 255) / 256, 256, 0, stream>>>(Wk, wkh, wkl, (int)(wsz / 4));
  cvt_split<<<(int)(wsz / 4 + 255) / 256, 256, 0, stream>>>(Wv, wvh, wvl, (int)(wsz / 4));
  cvt_split<<<(int)(wsz / 4 + 255) / 256, 256, 0, stream>>>(Wo, woh, wol, (int)(wsz / 4));
  cvt_split<<<(128 * 1024 / 4 + 255) / 256, 256, 0, stream>>>(Wab, wabh, wabl, 128 * 1024 / 4);

  for (int b0 = 0; b0 < BATCH; b0 += bc) {
    const float* xb = x + (size_t)b0 * per_b;
    const int M = bc * SEQ;
    const int n4 = (int)((size_t)bc * per_b / 4);
    dim3 gg(M / 128, DIMC / 128);
    dim3 gab(M / 128, 1);

    cvt_split<<<(n4 + 255) / 256, 256, 0, stream>>>(xb, xh, xl, n4);

    // q path
    gemm_bf16x3<<<gg, 256, 0, stream>>>(xh, xl, wqh, wql, bq, P, DIMC, DIMC, DIMC, 1);
    conv_kernel<<<dim3(M), 256, 0, stream>>>(P, cq, qb, 1);
    // k path
    gemm_bf16x3<<<gg, 256, 0, stream>>>(xh, xl, wkh, wkl, bk, P, DIMC, DIMC, DIMC, 1);
    conv_kernel<<<dim3(M), 256, 0, stream>>>(P, ck, kb, 1);
    // v path
    gemm_bf16x3<<<gg, 256, 0, stream>>>(xh, xl, wvh, wvl, bv, P, DIMC, DIMC, DIMC, 1);
    conv_kernel<<<dim3(M), 256, 0, stream>>>(P, cv, vb, 0);
    // gates
    gemm_bf16x3<<<gab, 256, 0, stream>>>(xh, xl, wabh, wabl, bab, abb, DIMC, 32, 32, 2);
    // recurrence pass 1: coef + checkpoints (serial, single-wave blocks, pipelined)
    scan2_kernel<<<dim3(bc * NHEAD * 8), 64, 0, stream>>>(kb, vb, abb, Cf, SCp);
    // recurrence pass 2: recompute outputs in parallel -> vb
    outp_kernel<<<dim3(SEQ / 64, bc * NHEAD), 256, 0, stream>>>(qb, kb, Cf, SCp, abb, vb);
    // output projection
    cvt_split<<<(n4 + 255) / 256, 256, 0, stream>>>(vb, xh, xl, n4);
    gemm_bf16x3<<<gg, 256, 0, stream>>>(xh, xl, woh, wol, bo, out + (size_t)b0 * per_b, DIMC, DIMC, DIMC, 0);
  }
}